// Round 1
// baseline (524.227 us; speedup 1.0000x reference)
//
#include <hip/hip_runtime.h>

// Problem constants: B=8, C=128, H=W=256, K=7, pad=3
#define Bc 8
#define Cc 128
#define Hc 256
#define Wc 256
#define HWc (Hc * Wc)          // 65536
#define CHWc (Cc * HWc)        // 8388608

// Channel chunking for the fused kernel: each block handles 32 channels of a
// 1024-pixel group; the 7x7 conv is recomputed redundantly per chunk (~5 us
// total across the grid, hidden under the 512 MiB stream) in exchange for 4x
// the block count (2048 blocks -> 8 blocks/CU -> full streaming TLP).
#define NCHUNK 4
#define CPB (Cc / NCHUNK)      // 32 channels per block

typedef float floatx4 __attribute__((ext_vector_type(4)));

// ---------------------------------------------------------------------------
// K1 (unchanged): pooled[b,h,w] = max_c input[b,c,h,w]
// One thread per 4 consecutive w positions (float4); loop 128 channels with
// stride-HW float4 loads (coalesced across the wave). Two independent max
// chains for ILP. Normal (caching) loads — we WANT input resident in L3
// for the fused kernel's re-read.
// ---------------------------------------------------------------------------
__global__ void __launch_bounds__(256) channel_max_kernel(const float* __restrict__ in,
                                                          float* __restrict__ pooled) {
    int tid = blockIdx.x * blockDim.x + threadIdx.x;   // 0 .. B*HW/4-1
    int e = tid << 2;                                  // flat index into [B,HW]
    int b = e / HWc;
    int s = e - b * HWc;
    const floatx4* base = (const floatx4*)(in + (size_t)b * CHWc + s);
    const int cstride = HWc / 4;                       // float4 stride between channels

    floatx4 m0 = base[0];
    floatx4 m1 = base[(size_t)cstride];
#pragma unroll 4
    for (int c = 2; c < Cc; c += 2) {
        floatx4 v0 = base[(size_t)c * cstride];
        floatx4 v1 = base[(size_t)(c + 1) * cstride];
        m0.x = fmaxf(m0.x, v0.x); m0.y = fmaxf(m0.y, v0.y);
        m0.z = fmaxf(m0.z, v0.z); m0.w = fmaxf(m0.w, v0.w);
        m1.x = fmaxf(m1.x, v1.x); m1.y = fmaxf(m1.y, v1.y);
        m1.z = fmaxf(m1.z, v1.z); m1.w = fmaxf(m1.w, v1.w);
    }
    floatx4 m;
    m.x = fmaxf(m0.x, m1.x); m.y = fmaxf(m0.y, m1.y);
    m.z = fmaxf(m0.z, m1.z); m.w = fmaxf(m0.w, m1.w);
    ((floatx4*)pooled)[tid] = m;
}

// ---------------------------------------------------------------------------
// K2 (fused conv + sigmoid + multiply):
//   attn = sigmoid(conv7x7(pooled) + bias) computed PER THREAD into registers
//   (4 pixels/thread), then a 32-channel loop multiplies the thread's own
//   input float4s by its register-held attn — the attn tensor is never
//   materialized to memory (kills the old K2 dispatch + 4 MiB round-trip).
// pooled (2 MiB) is L2-resident; weights in LDS.
// REVERSE pixel-group order: K1 just streamed the input through L3, tail
// hottest — read it first. Output stores nontemporal so the 256 MiB
// write-once stream doesn't evict cached input.
// ---------------------------------------------------------------------------
__global__ void __launch_bounds__(256) conv_mul_kernel(const float* __restrict__ in,
                                                       const float* __restrict__ pooled,
                                                       const float* __restrict__ wgt,
                                                       const float* __restrict__ bias,
                                                       float* __restrict__ out) {
    __shared__ float wsm[49];
    if (threadIdx.x < 49) wsm[threadIdx.x] = wgt[threadIdx.x];
    __syncthreads();

    unsigned bid = blockIdx.x;
    unsigned chunk = bid & (NCHUNK - 1);                   // 0..3: channel chunk
    unsigned pgBlocks = gridDim.x / NCHUNK;                // 512 pixel-group blocks
    unsigned pgb = pgBlocks - 1u - (bid >> 2);             // reverse traversal
    unsigned t = pgb * blockDim.x + threadIdx.x;           // 0 .. B*HW/4-1
    unsigned e = t << 2;                                   // flat pixel index [B,HW]
    unsigned b = e >> 16;                                  // / HWc (pow2)
    unsigned s = e & (HWc - 1);
    int h = (int)(s >> 8);                                 // / Wc
    int w0 = (int)(s & (Wc - 1));                          // % Wc

    // --- conv 7x7 + sigmoid for this thread's 4 pixels (registers only) ---
    const float* p = pooled + b * HWc;
    float attn[4];
#pragma unroll
    for (int k = 0; k < 4; ++k) {
        float acc = bias[0];
        int w = w0 + k;
#pragma unroll
        for (int i = 0; i < 7; ++i) {
            int hh = h - 3 + i;
            if ((unsigned)hh < (unsigned)Hc) {
                const float* row = p + hh * Wc;
#pragma unroll
                for (int j = 0; j < 7; ++j) {
                    int ww = w - 3 + j;
                    if ((unsigned)ww < (unsigned)Wc) {
                        acc = fmaf(row[ww], wsm[i * 7 + j], acc);
                    }
                }
            }
        }
        attn[k] = 1.0f / (1.0f + expf(-acc));
    }
    floatx4 a;
    a.x = attn[0]; a.y = attn[1]; a.z = attn[2]; a.w = attn[3];

    // --- stream this block's 32-channel chunk ---
    const size_t base = (size_t)b * CHWc + (size_t)chunk * CPB * HWc + s;
    const floatx4* ip = (const floatx4*)(in + base);
    float* op = out + base;
    const int cstride = HWc / 4;                           // float4 stride per channel
#pragma unroll 4
    for (int c = 0; c < CPB; ++c) {
        floatx4 v = ip[(size_t)c * cstride];
        v.x *= a.x;
        v.y *= a.y;
        v.z *= a.z;
        v.w *= a.w;
        __builtin_nontemporal_store(v, (floatx4*)(op) + (size_t)c * cstride);
    }
}

extern "C" void kernel_launch(void* const* d_in, const int* in_sizes, int n_in,
                              void* d_out, int out_size, void* d_ws, size_t ws_size,
                              hipStream_t stream) {
    const float* input  = (const float*)d_in[0];   // [8,128,256,256]
    const float* conv_w = (const float*)d_in[1];   // [1,1,7,7]
    const float* conv_b = (const float*)d_in[2];   // [1]
    float* out = (float*)d_out;

    // workspace layout: pooled [B*HW] only (attn is now register-resident)
    float* pooled = (float*)d_ws;

    // K1: 131072 threads -> 512 blocks of 256
    channel_max_kernel<<<(Bc * HWc / 4) / 256, 256, 0, stream>>>(input, pooled);

    // K2 fused: 512 pixel-group blocks x 4 channel chunks = 2048 blocks of 256
    conv_mul_kernel<<<NCHUNK * (Bc * HWc / 4) / 256, 256, 0, stream>>>(
        input, pooled, conv_w, conv_b, out);
}

// Round 2
// 498.199 us; speedup vs baseline: 1.0522x; 1.0522x over previous
//
#include <hip/hip_runtime.h>

// Problem constants: B=8, C=128, H=W=256, K=7, pad=3
#define Bc 8
#define Cc 128
#define Hc 256
#define Wc 256
#define HWc (Hc * Wc)          // 65536
#define CHWc (Cc * HWc)        // 8388608

typedef float floatx4 __attribute__((ext_vector_type(4)));

// ---------------------------------------------------------------------------
// K1: pooled[b,h,w] = max_c input[b,c,h,w]
// One thread per 4 consecutive w positions (float4); loop 128 channels with
// stride-HW float4 loads (coalesced across the wave). FOUR independent max
// chains for ILP (was 2). Normal (caching) loads — we WANT input resident
// in L3 for K3's re-read; K1's channel-major traversal ends at c=127, so
// the high channels are hottest in L3 when K3 starts.
// ---------------------------------------------------------------------------
__global__ void __launch_bounds__(256) channel_max_kernel(const float* __restrict__ in,
                                                          float* __restrict__ pooled) {
    int tid = blockIdx.x * blockDim.x + threadIdx.x;   // 0 .. B*HW/4-1
    int e = tid << 2;                                  // flat index into [B,HW]
    int b = e >> 16;                                   // / HWc (pow2)
    int s = e & (HWc - 1);
    const floatx4* base = (const floatx4*)(in + (size_t)b * CHWc + s);
    const int cstride = HWc / 4;                       // float4 stride between channels

    floatx4 m0 = base[0];
    floatx4 m1 = base[(size_t)cstride];
    floatx4 m2 = base[(size_t)(2 * cstride)];
    floatx4 m3 = base[(size_t)(3 * cstride)];
#pragma unroll 4
    for (int c = 4; c < Cc; c += 4) {
        floatx4 v0 = base[(size_t)c * cstride];
        floatx4 v1 = base[(size_t)(c + 1) * cstride];
        floatx4 v2 = base[(size_t)(c + 2) * cstride];
        floatx4 v3 = base[(size_t)(c + 3) * cstride];
        m0.x = fmaxf(m0.x, v0.x); m0.y = fmaxf(m0.y, v0.y);
        m0.z = fmaxf(m0.z, v0.z); m0.w = fmaxf(m0.w, v0.w);
        m1.x = fmaxf(m1.x, v1.x); m1.y = fmaxf(m1.y, v1.y);
        m1.z = fmaxf(m1.z, v1.z); m1.w = fmaxf(m1.w, v1.w);
        m2.x = fmaxf(m2.x, v2.x); m2.y = fmaxf(m2.y, v2.y);
        m2.z = fmaxf(m2.z, v2.z); m2.w = fmaxf(m2.w, v2.w);
        m3.x = fmaxf(m3.x, v3.x); m3.y = fmaxf(m3.y, v3.y);
        m3.z = fmaxf(m3.z, v3.z); m3.w = fmaxf(m3.w, v3.w);
    }
    m0.x = fmaxf(m0.x, m1.x); m0.y = fmaxf(m0.y, m1.y);
    m0.z = fmaxf(m0.z, m1.z); m0.w = fmaxf(m0.w, m1.w);
    m2.x = fmaxf(m2.x, m3.x); m2.y = fmaxf(m2.y, m3.y);
    m2.z = fmaxf(m2.z, m3.z); m2.w = fmaxf(m2.w, m3.w);
    floatx4 m;
    m.x = fmaxf(m0.x, m2.x); m.y = fmaxf(m0.y, m2.y);
    m.z = fmaxf(m0.z, m2.z); m.w = fmaxf(m0.w, m2.w);
    ((floatx4*)pooled)[tid] = m;
}

// ---------------------------------------------------------------------------
// K2: attn[b,h,w] = sigmoid( conv7x7(pooled, wgt, zero-pad 3) + bias )
// One thread per pixel; pooled (2 MiB) is L2-resident. Weights in LDS.
// (~10 us — unchanged, proven correct.)
// ---------------------------------------------------------------------------
__global__ void __launch_bounds__(256) conv_sigmoid_kernel(const float* __restrict__ pooled,
                                                           const float* __restrict__ wgt,
                                                           const float* __restrict__ bias,
                                                           float* __restrict__ attn) {
    __shared__ float wsm[49];
    if (threadIdx.x < 49) wsm[threadIdx.x] = wgt[threadIdx.x];
    __syncthreads();

    int tid = blockIdx.x * blockDim.x + threadIdx.x;   // 0 .. B*HW-1
    int b = tid / HWc;
    int s = tid - b * HWc;
    int h = s >> 8;            // / Wc
    int w = s & (Wc - 1);      // % Wc
    const float* p = pooled + b * HWc;

    float acc = bias[0];
#pragma unroll
    for (int i = 0; i < 7; ++i) {
        int hh = h - 3 + i;
        if ((unsigned)hh < (unsigned)Hc) {
            const float* row = p + hh * Wc;
#pragma unroll
            for (int j = 0; j < 7; ++j) {
                int ww = w - 3 + j;
                if ((unsigned)ww < (unsigned)Wc) {
                    acc = fmaf(row[ww], wsm[i * 7 + j], acc);
                }
            }
        }
    }
    attn[tid] = 1.0f / (1.0f + expf(-acc));
}

// ---------------------------------------------------------------------------
// K3: out[b,c,h,w] = input[b,c,h,w] * attn[b,h,w]
// EIGHT channels per thread: one attn float4 load amortized over 8
// channel-strided input float4s (attn traffic /8, 8 loads in flight for
// ILP). Group-major thread mapping + REVERSE block order: the grid's 4
// sequential resident rounds start at channels 96..127 / pixel tail —
// exactly what K1 left hottest in L3 (input = 256 MiB = L3 capacity).
// Output stores nontemporal so the 256 MiB write-once stream doesn't
// evict the cached input.
// ---------------------------------------------------------------------------
#define K3_CPT 8               // channels per thread
__global__ void __launch_bounds__(256) mul_kernel(const float* __restrict__ in,
                                                  const float* __restrict__ attn,
                                                  float* __restrict__ out) {
    unsigned rb = gridDim.x - 1u - blockIdx.x;              // reverse traversal
    unsigned t = rb * blockDim.x + threadIdx.x;             // 0 .. B*HW/4*(C/8)-1
    unsigned pos = t & (Bc * HWc / 4 - 1);                  // f4 index into [B,HW]
    unsigned g = t >> 17;                                   // 8-channel group, 0..15
    unsigned e = pos << 2;                                  // flat float index [B,HW]
    unsigned b = e >> 16;                                   // / HWc
    unsigned s = e & (HWc - 1);

    floatx4 a = ((const floatx4*)attn)[pos];                // one attn load / 8 ch

    const size_t base = (size_t)b * CHWc + (size_t)(g * K3_CPT) * HWc + s;
    const float* ip = in + base;
    float* op = out + base;

    floatx4 v[K3_CPT];
#pragma unroll
    for (int k = 0; k < K3_CPT; ++k)
        v[k] = *(const floatx4*)(ip + (size_t)k * HWc);     // 8 loads in flight
#pragma unroll
    for (int k = 0; k < K3_CPT; ++k) {
        v[k].x *= a.x;
        v[k].y *= a.y;
        v[k].z *= a.z;
        v[k].w *= a.w;
        __builtin_nontemporal_store(v[k], (floatx4*)(op + (size_t)k * HWc));
    }
}

extern "C" void kernel_launch(void* const* d_in, const int* in_sizes, int n_in,
                              void* d_out, int out_size, void* d_ws, size_t ws_size,
                              hipStream_t stream) {
    const float* input  = (const float*)d_in[0];   // [8,128,256,256]
    const float* conv_w = (const float*)d_in[1];   // [1,1,7,7]
    const float* conv_b = (const float*)d_in[2];   // [1]
    float* out = (float*)d_out;

    // workspace layout: pooled [B*HW] then attn [B*HW]
    float* pooled = (float*)d_ws;
    float* attn   = pooled + (size_t)Bc * HWc;

    // K1: 131072 threads -> 512 blocks of 256
    channel_max_kernel<<<(Bc * HWc / 4) / 256, 256, 0, stream>>>(input, pooled);

    // K2: 524288 threads -> 2048 blocks of 256
    conv_sigmoid_kernel<<<(Bc * HWc) / 256, 256, 0, stream>>>(pooled, conv_w, conv_b, attn);

    // K3: 2097152 threads -> 8192 blocks of 256
    mul_kernel<<<(Bc * HWc / 4) * (Cc / K3_CPT) / 256, 256, 0, stream>>>(input, attn, out);
}

// Round 3
// 493.492 us; speedup vs baseline: 1.0623x; 1.0095x over previous
//
#include <hip/hip_runtime.h>

// Problem constants: B=8, C=128, H=W=256, K=7, pad=3
#define Bc 8
#define Cc 128
#define Hc 256
#define Wc 256
#define HWc (Hc * Wc)          // 65536 = 2^16
#define CHWc (Cc * HWc)        // 8388608 = 2^23

// L3-chunked pipeline: the input (256 MiB) exactly equals Infinity Cache
// capacity, so a whole-problem K1->K3 pass cannot keep the re-read resident.
// Process 4 images (128 MiB) at a time: K1(c) streams the chunk through L3,
// K3(c) re-reads it immediately while it is GUARANTEED resident (128 << 256
// MiB), so K3 becomes write-bound instead of read+write bound.
#define IMGS 4                 // images per chunk
#define NCHUNK (Bc / IMGS)     // 2 chunks

typedef float floatx4 __attribute__((ext_vector_type(4)));

// ---------------------------------------------------------------------------
// K1 (per 4-image chunk): pooled[b,h,w] = max_c input[b,c,h,w]
// One thread per 4 consecutive w positions (float4); loop 128 channels with
// stride-HW float4 loads (coalesced across the wave). Four independent max
// chains; loads are all independent so ~8-12 stay in flight per thread.
// 256 blocks = 1 block/CU, 4 waves/CU: 4*64*16B*ILP >= latency-BW product,
// still saturates HBM. Normal (caching) loads — the POINT is to leave the
// chunk resident in L3 for K3's re-read.
// ---------------------------------------------------------------------------
__global__ void __launch_bounds__(256) channel_max_kernel(const float* __restrict__ in,
                                                          float* __restrict__ pooled,
                                                          int b0) {
    int tid = blockIdx.x * blockDim.x + threadIdx.x;   // 0 .. IMGS*HW/4-1
    int e = tid << 2;                                  // flat index into [IMGS,HW]
    int bl = e >> 16;                                  // local image 0..3
    int s = e & (HWc - 1);
    const floatx4* base = (const floatx4*)(in + (size_t)(b0 + bl) * CHWc + s);
    const int cstride = HWc / 4;                       // float4 stride between channels

    floatx4 m0 = base[0];
    floatx4 m1 = base[(size_t)cstride];
    floatx4 m2 = base[(size_t)(2 * cstride)];
    floatx4 m3 = base[(size_t)(3 * cstride)];
#pragma unroll 4
    for (int c = 4; c < Cc; c += 4) {
        floatx4 v0 = base[(size_t)c * cstride];
        floatx4 v1 = base[(size_t)(c + 1) * cstride];
        floatx4 v2 = base[(size_t)(c + 2) * cstride];
        floatx4 v3 = base[(size_t)(c + 3) * cstride];
        m0.x = fmaxf(m0.x, v0.x); m0.y = fmaxf(m0.y, v0.y);
        m0.z = fmaxf(m0.z, v0.z); m0.w = fmaxf(m0.w, v0.w);
        m1.x = fmaxf(m1.x, v1.x); m1.y = fmaxf(m1.y, v1.y);
        m1.z = fmaxf(m1.z, v1.z); m1.w = fmaxf(m1.w, v1.w);
        m2.x = fmaxf(m2.x, v2.x); m2.y = fmaxf(m2.y, v2.y);
        m2.z = fmaxf(m2.z, v2.z); m2.w = fmaxf(m2.w, v2.w);
        m3.x = fmaxf(m3.x, v3.x); m3.y = fmaxf(m3.y, v3.y);
        m3.z = fmaxf(m3.z, v3.z); m3.w = fmaxf(m3.w, v3.w);
    }
    m0.x = fmaxf(m0.x, m1.x); m0.y = fmaxf(m0.y, m1.y);
    m0.z = fmaxf(m0.z, m1.z); m0.w = fmaxf(m0.w, m1.w);
    m2.x = fmaxf(m2.x, m3.x); m2.y = fmaxf(m2.y, m3.y);
    m2.z = fmaxf(m2.z, m3.z); m2.w = fmaxf(m2.w, m3.w);
    floatx4 m;
    m.x = fmaxf(m0.x, m2.x); m.y = fmaxf(m0.y, m2.y);
    m.z = fmaxf(m0.z, m2.z); m.w = fmaxf(m0.w, m2.w);
    ((floatx4*)(pooled + (size_t)b0 * HWc))[tid] = m;
}

// ---------------------------------------------------------------------------
// K2 (per 4-image chunk): attn = sigmoid( conv7x7(pooled, zero-pad 3) + bias )
// One thread per pixel; chunk's pooled (1 MiB) is L2/L3-hot. Weights in LDS.
// ---------------------------------------------------------------------------
__global__ void __launch_bounds__(256) conv_sigmoid_kernel(const float* __restrict__ pooled,
                                                           const float* __restrict__ wgt,
                                                           const float* __restrict__ bias,
                                                           float* __restrict__ attn,
                                                           int b0) {
    __shared__ float wsm[49];
    if (threadIdx.x < 49) wsm[threadIdx.x] = wgt[threadIdx.x];
    __syncthreads();

    int tid = blockIdx.x * blockDim.x + threadIdx.x;   // 0 .. IMGS*HW-1
    int bl = tid >> 16;                                // local image
    int s = tid & (HWc - 1);
    int h = s >> 8;            // / Wc
    int w = s & (Wc - 1);      // % Wc
    const float* p = pooled + (size_t)(b0 + bl) * HWc;

    float acc = bias[0];
#pragma unroll
    for (int i = 0; i < 7; ++i) {
        int hh = h - 3 + i;
        if ((unsigned)hh < (unsigned)Hc) {
            const float* row = p + hh * Wc;
#pragma unroll
            for (int j = 0; j < 7; ++j) {
                int ww = w - 3 + j;
                if ((unsigned)ww < (unsigned)Wc) {
                    acc = fmaf(row[ww], wsm[i * 7 + j], acc);
                }
            }
        }
    }
    attn[(size_t)(b0 + bl) * HWc + s] = 1.0f / (1.0f + expf(-acc));
}

// ---------------------------------------------------------------------------
// K3 (per 4-image chunk): out = input * attn (broadcast over channels)
// Simple 1-float4-per-thread form (proven fastest, r0 vs r2). The chunk's
// input is L3-resident from K1(c), so reads hit L3 and the kernel is
// HBM-write-bound. Nontemporal stores keep the write-once output stream
// from evicting the chunk input.
// ---------------------------------------------------------------------------
__global__ void __launch_bounds__(256) mul_kernel(const float* __restrict__ in,
                                                  const float* __restrict__ attn,
                                                  float* __restrict__ out,
                                                  int b0) {
    unsigned t = blockIdx.x * blockDim.x + threadIdx.x;     // 0 .. IMGS*CHW/4-1
    unsigned e = t << 2;                                    // flat into [IMGS,C,H,W]
    unsigned bl = e >> 23;                                  // / CHWc
    unsigned rem = e & (CHWc - 1);
    unsigned s = rem & (HWc - 1);
    size_t idx = (size_t)(b0 + bl) * CHWc + rem;

    floatx4 v = *(const floatx4*)(in + idx);
    floatx4 a = *(const floatx4*)(attn + (size_t)(b0 + bl) * HWc + s);
    v.x *= a.x;
    v.y *= a.y;
    v.z *= a.z;
    v.w *= a.w;
    __builtin_nontemporal_store(v, (floatx4*)(out + idx));
}

extern "C" void kernel_launch(void* const* d_in, const int* in_sizes, int n_in,
                              void* d_out, int out_size, void* d_ws, size_t ws_size,
                              hipStream_t stream) {
    const float* input  = (const float*)d_in[0];   // [8,128,256,256]
    const float* conv_w = (const float*)d_in[1];   // [1,1,7,7]
    const float* conv_b = (const float*)d_in[2];   // [1]
    float* out = (float*)d_out;

    // workspace layout: pooled [B*HW] then attn [B*HW]
    float* pooled = (float*)d_ws;
    float* attn   = pooled + (size_t)Bc * HWc;

    for (int c = 0; c < NCHUNK; ++c) {
        int b0 = c * IMGS;
        // K1(c): 65536 threads -> 256 blocks of 256
        channel_max_kernel<<<(IMGS * HWc / 4) / 256, 256, 0, stream>>>(input, pooled, b0);
        // K2(c): 262144 threads -> 1024 blocks of 256
        conv_sigmoid_kernel<<<(IMGS * HWc) / 256, 256, 0, stream>>>(pooled, conv_w, conv_b,
                                                                    attn, b0);
        // K3(c): 8388608 threads -> 32768 blocks of 256
        mul_kernel<<<(IMGS * CHWc / 4) / 256, 256, 0, stream>>>(input, attn, out, b0);
    }
}